// Round 5
// baseline (98.507 us; speedup 1.0000x reference)
//
#include <hip/hip_runtime.h>
#include <hip/hip_bf16.h>

typedef unsigned short u16;
typedef float  floatx4 __attribute__((ext_vector_type(4)));
typedef short  bf16x8  __attribute__((ext_vector_type(8)));

#define GK 4224   // extended K = 4096 + 64 lora cols + 64 zero pad (2*33*64)

__device__ __forceinline__ u16 f2bf_rne(float f) {
  union { float f; unsigned int u; } v; v.f = f;
  unsigned int r = v.u + 0x7FFFu + ((v.u >> 16) & 1u);
  return (u16)(r >> 16);
}
__device__ __forceinline__ float bf2f(u16 h) {
  union { unsigned int u; float f; } v; v.u = ((unsigned int)h) << 16;
  return v.f;
}

// ===========================================================================
// In-register FWHT-4096 per block (4 waves): H4096 = H64(rows) (x) H64(cols).
// ===========================================================================
__device__ __forceinline__ void fwht4096_regs(float v[16], float* X, int w, int l) {
#pragma unroll
  for (int h = 1; h < 64; h <<= 1) {
#pragma unroll
    for (int k = 0; k < 16; ++k) {
      float o = __shfl_xor(v[k], h, 64);
      v[k] = (l & h) ? (o - v[k]) : (v[k] + o);
    }
  }
#pragma unroll
  for (int k = 0; k < 16; ++k) X[(w * 16 + k) * 64 + l] = v[k];
  __syncthreads();
  float s4 = (w & 1) ? -1.f : 1.f;
  float s5 = (w & 2) ? -1.f : 1.f;
#pragma unroll
  for (int k = 0; k < 16; ++k) {
    float x00 = X[(k     ) * 64 + l];
    float x01 = X[(k + 16) * 64 + l];
    float x10 = X[(k + 32) * 64 + l];
    float x11 = X[(k + 48) * 64 + l];
    v[k] = (x00 + s4 * x01) + s5 * (x10 + s4 * x11);
  }
#pragma unroll
  for (int h = 1; h < 16; h <<= 1) {
#pragma unroll
    for (int k = 0; k < 16; ++k) {
      if (!(k & h)) { float a = v[k], b = v[k ^ h]; v[k] = a + b; v[k ^ h] = a - b; }
    }
  }
}

// ---------------------------------------------------------------------------
// Kernel 1: decode E8P -> integer weights (exact in bf16), pitched rows of GK.
// ---------------------------------------------------------------------------
__global__ void decode_kernel(const int* __restrict__ codes,
                              const int* __restrict__ grid,
                              u16* __restrict__ Wd) {
  __shared__ int sgrid[256];
  int t = threadIdx.x;
  sgrid[t] = grid[t & 255];
  __syncthreads();
  int idx = blockIdx.x * 256 + t;            // 0 .. 4096*512-1
  int c = codes[idx];
  int abs_idx   = c & 255;
  int sign_bits = (c >> 8) & 127;
  int dlt       = 2 * ((c >> 15) & 1) - 1;   // 4*delta = ±1
  int packed    = sgrid[abs_idx];
  int par       = __popc(sign_bits) & 1;
  u16 w[8];
#pragma unroll
  for (int j = 0; j < 8; ++j) {
    int nib = (packed >> (4 * j)) & 15;
    int neg = (j < 7) ? ((sign_bits >> j) & 1) : par;
    int val = (neg ? -2 * nib : 2 * nib) + dlt;
    w[j] = f2bf_rne((float)val);             // exact: |val| <= 29
  }
  uint4 pk;
  pk.x = (unsigned)w[0] | ((unsigned)w[1] << 16);
  pk.y = (unsigned)w[2] | ((unsigned)w[3] << 16);
  pk.z = (unsigned)w[4] | ((unsigned)w[5] << 16);
  pk.w = (unsigned)w[6] | ((unsigned)w[7] << 16);
  int m = idx >> 9, g = idx & 511;
  ((uint4*)Wd)[(size_t)m * (GK / 8) + g] = pk;   // GK/8 = 528 uint4 per row
}

// ---------------------------------------------------------------------------
// Kernel 2: At[r][m] = bf16( (0.8*263.68/(4096*Wscale)) * H_M(SV o loraA[:,r]) )
// ---------------------------------------------------------------------------
__global__ __launch_bounds__(256) void prep_A_kernel(const float* __restrict__ loraA,
                                                     const float* __restrict__ SV,
                                                     const float* __restrict__ WscaleP,
                                                     u16* __restrict__ At) {
  __shared__ float X[4096];
  int r = blockIdx.x, t = threadIdx.x, l = t & 63, w = t >> 6;
  float v[16];
#pragma unroll
  for (int k = 0; k < 16; ++k) {
    int i = (w * 16 + k) * 64 + l;
    v[k] = loraA[(size_t)i * 64 + r] * SV[i];
  }
  fwht4096_regs(v, X, w, l);
  float factor = (0.8f * 263.68f / 4096.0f) / WscaleP[0];
#pragma unroll
  for (int k = 0; k < 16; ++k) {
    int i = (w * 16 + k) * 64 + l;
    At[(size_t)r * 4096 + i] = f2bf_rne(v[k] * factor);
  }
}

// ---------------------------------------------------------------------------
// Kernel 3: transpose At[64][4096] into Wd tail cols 4096..4159; zero 4160..4223
// ---------------------------------------------------------------------------
__global__ void transA_kernel(const u16* __restrict__ At, u16* __restrict__ Wd) {
  __shared__ u16 T[64][65];
  int m0 = blockIdx.x * 64, t = threadIdx.x;
  int c = t & 63, q = t >> 6;
#pragma unroll
  for (int j = 0; j < 16; ++j) {
    int r = q * 16 + j;
    T[r][c] = At[(size_t)r * 4096 + m0 + c];
  }
  __syncthreads();
#pragma unroll
  for (int j = 0; j < 16; ++j) {
    int m = q * 16 + j;
    Wd[(size_t)(m0 + m) * GK + 4096 + c] = T[c][m];
    Wd[(size_t)(m0 + m) * GK + 4160 + c] = 0;   // K pad
  }
}

// ---------------------------------------------------------------------------
// Kernel 4: Bh[r][n] = bf16( Hnorm(loraB[r] o SU)[n] )  (orthonormal FWHT)
// lr[s,r] = x[s].loraB[r] = (x oSU).(loraB[r] oSU) = u[s].Bh[r]  (Parseval)
// ---------------------------------------------------------------------------
__global__ __launch_bounds__(256) void prep_B_kernel(const float* __restrict__ loraB,
                                                     const float* __restrict__ SU,
                                                     u16* __restrict__ Bh) {
  __shared__ float X[4096];
  int r = blockIdx.x, t = threadIdx.x, l = t & 63, w = t >> 6;
  float v[16];
#pragma unroll
  for (int k = 0; k < 16; ++k) {
    int i = (w * 16 + k) * 64 + l;
    v[k] = loraB[(size_t)r * 4096 + i] * SU[i];
  }
  fwht4096_regs(v, X, w, l);
#pragma unroll
  for (int k = 0; k < 16; ++k) {
    int i = (w * 16 + k) * 64 + l;
    Bh[(size_t)r * 4096 + i] = f2bf_rne(v[k] * 0.015625f);
  }
}

// ---------------------------------------------------------------------------
// Kernel 5: u[s][0..4095] = bf16( H(x[s] o SU) / 64 )
// ---------------------------------------------------------------------------
__global__ __launch_bounds__(256) void fwht_u_kernel(const float* __restrict__ x,
                                                     const float* __restrict__ SU,
                                                     u16* __restrict__ u) {
  __shared__ float X[4096];
  int s = blockIdx.x, t = threadIdx.x, l = t & 63, w = t >> 6;
  const float* xr = x + (size_t)s * 4096;
  float v[16];
#pragma unroll
  for (int k = 0; k < 16; ++k) {
    int i = (w * 16 + k) * 64 + l;
    v[k] = xr[i] * SU[i];
  }
  fwht4096_regs(v, X, w, l);
  u16* ur = u + (size_t)s * GK;
#pragma unroll
  for (int k = 0; k < 16; ++k) {
    int i = (w * 16 + k) * 64 + l;
    ur[i] = f2bf_rne(v[k] * 0.015625f);
  }
}

// ---------------------------------------------------------------------------
// Staging helpers (16B global_load_lds, XOR-swizzled source; verified r2-r4)
// ---------------------------------------------------------------------------
__device__ __forceinline__ void stage64(const u16* __restrict__ src, int rowBase,
                                        int kt, char* ldsBase, int wg, int l) {
#pragma unroll
  for (int it = 0; it < 4; ++it) {
    int ci  = it * 4 + wg;                // 1KB chunk index (wave-uniform)
    int row = ci * 8 + (l >> 3);
    int cg  = (l & 7) ^ ((l >> 3) & 7);   // pre-swizzled source 16B-slot
    const u16* gp = src + (size_t)(rowBase + row) * GK + kt + cg * 8;
    __builtin_amdgcn_global_load_lds(
        (const __attribute__((address_space(1))) void*)gp,
        (__attribute__((address_space(3))) void*)(ldsBase + ci * 1024), 16, 0, 0);
  }
}

// 64 rows x 64 cols, pitch 4096 (Bh)
__device__ __forceinline__ void stage64n(const u16* __restrict__ src,
                                         int kt, char* ldsBase, int wg, int l) {
#pragma unroll
  for (int it = 0; it < 2; ++it) {
    int ci  = it * 4 + wg;
    int row = ci * 8 + (l >> 3);
    int cg  = (l & 7) ^ ((l >> 3) & 7);
    const u16* gp = src + (size_t)row * 4096 + kt + cg * 8;
    __builtin_amdgcn_global_load_lds(
        (const __attribute__((address_space(1))) void*)gp,
        (__attribute__((address_space(3))) void*)(ldsBase + ci * 1024), 16, 0, 0);
  }
}

// ---------------------------------------------------------------------------
// Kernel 6: lr partials. P[by][s][r] = sum_{k in chunk by} u[s,k]*Bh[r,k]
// ---------------------------------------------------------------------------
__global__ __launch_bounds__(256) void lr_gemm_kernel(
    const u16* __restrict__ U,    // [1024][GK]
    const u16* __restrict__ Bh,   // [64][4096]
    float* __restrict__ P) {      // [4][1024][64]
  __shared__ char lds[49152];     // A0|A1 (16KB each) + B0|B1 (8KB each)
  int t = threadIdx.x, w = t >> 6, l = t & 63;
  int s0 = blockIdx.x * 128, k0 = blockIdx.y * 1024;
  int lr16 = l & 15, lk = l >> 4;
  char* ldsA = lds;
  char* ldsB = lds + 32768;

  floatx4 acc[2][4];
#pragma unroll
  for (int i = 0; i < 2; ++i)
#pragma unroll
    for (int j = 0; j < 4; ++j) acc[i][j] = (floatx4){0.f, 0.f, 0.f, 0.f};

  const int NT = 16;   // 16 * 64 = 1024
  stage64 (U,  s0, k0,      ldsA,         w, l);
  stage64n(Bh,     k0,      ldsB,         w, l);
  stage64 (U,  s0, k0 + 64, ldsA + 16384, w, l);
  stage64n(Bh,     k0 + 64, ldsB + 8192,  w, l);
  asm volatile("s_waitcnt vmcnt(6)" ::: "memory");
  __builtin_amdgcn_s_barrier();

  for (int i = 0; i < NT; ++i) {
    int buf = i & 1;
    const char* sAc = ldsA + buf * 16384;
    const char* sBc = ldsB + buf * 8192;
    bf16x8 a[2][2], b[4][2];
#pragma unroll
    for (int ii = 0; ii < 2; ++ii)
#pragma unroll
      for (int ks = 0; ks < 2; ++ks) {
        int row = w * 32 + ii * 16 + lr16;
        int kb  = ks * 64 + lk * 16;
        a[ii][ks] = *(const bf16x8*)(sAc + (row << 7) + (kb ^ ((row & 7) << 4)));
      }
#pragma unroll
    for (int jj = 0; jj < 4; ++jj)
#pragma unroll
      for (int ks = 0; ks < 2; ++ks) {
        int row = jj * 16 + lr16;
        int kb  = ks * 64 + lk * 16;
        b[jj][ks] = *(const bf16x8*)(sBc + (row << 7) + (kb ^ ((row & 7) << 4)));
      }
    asm volatile("s_waitcnt lgkmcnt(0)" ::: "memory");
    __builtin_amdgcn_sched_barrier(0);
    bool do_stage = (i + 2) < NT;
    if (do_stage) {
      __builtin_amdgcn_s_barrier();
      stage64 (U,  s0, k0 + (i + 2) * 64, ldsA + buf * 16384, w, l);
      stage64n(Bh,     k0 + (i + 2) * 64, ldsB + buf * 8192,  w, l);
    }
#pragma unroll
    for (int ks = 0; ks < 2; ++ks)
#pragma unroll
      for (int ii = 0; ii < 2; ++ii)
#pragma unroll
        for (int jj = 0; jj < 4; ++jj)
          acc[ii][jj] = __builtin_amdgcn_mfma_f32_16x16x32_bf16(
              a[ii][ks], b[jj][ks], acc[ii][jj], 0, 0, 0);
    if (i + 1 < NT) {
      if (do_stage) asm volatile("s_waitcnt vmcnt(6)" ::: "memory");
      else          asm volatile("s_waitcnt vmcnt(0)" ::: "memory");
      __builtin_amdgcn_s_barrier();
    }
  }
  float* Pb = P + (size_t)blockIdx.y * 65536;
#pragma unroll
  for (int ii = 0; ii < 2; ++ii)
#pragma unroll
    for (int jj = 0; jj < 4; ++jj) {
      int col  = jj * 16 + lr16;
      int rowb = s0 + w * 32 + ii * 16 + lk * 4;
#pragma unroll
      for (int q = 0; q < 4; ++q)
        Pb[(size_t)(rowb + q) * 64 + col] = acc[ii][jj][q];
    }
}

// ---------------------------------------------------------------------------
// Kernel 7: lr tail: u[s][4096+r] = bf16( sum_c P[c][s][r] ); zero K pad.
// ---------------------------------------------------------------------------
__global__ void lr_reduce_kernel(const float* __restrict__ P, u16* __restrict__ u) {
  int idx = blockIdx.x * 256 + threadIdx.x;   // 0..65535
  float s = P[idx] + P[65536 + idx] + P[131072 + idx] + P[196608 + idx];
  int ss = idx >> 6, rr = idx & 63;
  u[(size_t)ss * GK + 4096 + rr] = f2bf_rne(s);
  u[(size_t)ss * GK + 4160 + rr] = 0;         // K pad
}

// ---------------------------------------------------------------------------
// Kernel 8: GEMM partials. zP[s][g][m] = bf16( sum_{k in half g} A[s,k]*B[m,k] )
// Grid (32, 8, 2): K split across TWO INDEPENDENT 256-thread blocks (64 KiB
// LDS -> 2 blocks/CU, barrier-decoupled phase overlap). Per block: 128x128
// tile, BK=64 double-buffered, interleaved ks0-reads/ks1-reads/MFMA-ks0/
// stage/MFMA-ks1 with counted vmcnt. zP lives inside d_out ([1024][2][4096]
// u16 = exactly out's 32 MB; final_kernel reads row s before writing row s).
// ---------------------------------------------------------------------------
__global__ __launch_bounds__(256) void gemm_kernel(
    const u16* __restrict__ A,   // u  [1024][GK]
    const u16* __restrict__ B,   // Wd [4096][GK]
    u16* __restrict__ zP) {      // [1024][2][4096] bf16 (aliases d_out)
  __shared__ char lds[65536];    // A0 A1 B0 B1 (16KB each)
  int t = threadIdx.x, w = t >> 6, l = t & 63;
  int m0 = blockIdx.x * 128, s0 = blockIdx.y * 128, g = blockIdx.z;
  int wm = w >> 1, wn = w & 1;
  int lr16 = l & 15, lk = l >> 4;

  floatx4 acc[4][4];
#pragma unroll
  for (int i = 0; i < 4; ++i)
#pragma unroll
    for (int j = 0; j < 4; ++j) acc[i][j] = (floatx4){0.f, 0.f, 0.f, 0.f};

  const int NT = 33;                       // 33*64 = 2112 per half
  int kb0 = g * 2112;

  stage64(A, s0, kb0,      lds,         w, l);
  stage64(B, m0, kb0,      lds + 32768, w, l);
  stage64(A, s0, kb0 + 64, lds + 16384, w, l);
  stage64(B, m0, kb0 + 64, lds + 49152, w, l);
  asm volatile("s_waitcnt vmcnt(8)" ::: "memory");
  __builtin_amdgcn_s_barrier();

  for (int i = 0; i < NT; ++i) {
    int buf = i & 1;
    const char* sAc = lds + buf * 16384;
    const char* sBc = lds + 32768 + buf * 16384;
    bf16x8 a[4][2], b[4][2];
    // ks=0 fragment reads
#pragma unroll
    for (int ii = 0; ii < 4; ++ii) {
      int row = wm * 64 + ii * 16 + lr16;
      a[ii][0] = *(const bf16x8*)(sAc + (row << 7) + ((lk * 16) ^ ((row & 7) << 4)));
    }
#pragma unroll
    for (int jj = 0; jj < 4; ++jj) {
      int row = wn * 64 + jj * 16 + lr16;
      b[jj][0] = *(const bf16x8*)(sBc + (row << 7) + ((lk * 16) ^ ((row & 7) << 4)));
    }
    // ks=1 fragment reads (in flight under MFMA ks=0)
#pragma unroll
    for (int ii = 0; ii < 4; ++ii) {
      int row = wm * 64 + ii * 16 + lr16;
      a[ii][1] = *(const bf16x8*)(sAc + (row << 7) + ((64 + lk * 16) ^ ((row & 7) << 4)));
    }
#pragma unroll
    for (int jj = 0; jj < 4; ++jj) {
      int row = wn * 64 + jj * 16 + lr16;
      b[jj][1] = *(const bf16x8*)(sBc + (row << 7) + ((64 + lk * 16) ^ ((row & 7) << 4)));
    }
    // MFMA ks=0 (register deps give compiler-counted lgkmcnt overlap)
#pragma unroll
    for (int ii = 0; ii < 4; ++ii)
#pragma unroll
      for (int jj = 0; jj < 4; ++jj)
        acc[ii][jj] = __builtin_amdgcn_mfma_f32_16x16x32_bf16(
            a[ii][0], b[jj][0], acc[ii][jj], 0, 0, 0);
    asm volatile("s_waitcnt lgkmcnt(0)" ::: "memory");   // all reads of buf done
    __builtin_amdgcn_s_barrier();
    bool do_stage = (i + 2) < NT;          // block-uniform
    if (do_stage) {
      stage64(A, s0, kb0 + (i + 2) * 64, lds + buf * 16384, w, l);
      stage64(B, m0, kb0 + (i + 2) * 64, lds + 32768 + buf * 16384, w, l);
    }
    // MFMA ks=1 (overlaps staging issue)
#pragma unroll
    for (int ii = 0; ii < 4; ++ii)
#pragma unroll
      for (int jj = 0; jj < 4; ++jj)
        acc[ii][jj] = __builtin_amdgcn_mfma_f32_16x16x32_bf16(
            a[ii][1], b[jj][1], acc[ii][jj], 0, 0, 0);
    if (i + 1 < NT) {
      if (do_stage) asm volatile("s_waitcnt vmcnt(8)" ::: "memory");
      else          asm volatile("s_waitcnt vmcnt(0)" ::: "memory");
      __builtin_amdgcn_s_barrier();
    }
  }
  // C/D layout: col = lane&15, row = (lane>>4)*4 + q
#pragma unroll
  for (int ii = 0; ii < 4; ++ii)
#pragma unroll
    for (int jj = 0; jj < 4; ++jj) {
      int col  = m0 + wn * 64 + jj * 16 + lr16;
      int rowb = s0 + wm * 64 + ii * 16 + lk * 4;
#pragma unroll
      for (int q = 0; q < 4; ++q)
        zP[(size_t)(rowb + q) * 8192 + g * 4096 + col] = f2bf_rne(acc[ii][jj][q]);
    }
}

// ---------------------------------------------------------------------------
// Kernel 9: out[s][i] = (Wscale/263.68) * SV[i] * H(zP[s][0]+zP[s][1])[i]
// zP aliases out rows: block s reads bytes [s*16K, s*16K+16K) (as u16) and
// writes the same range (as f32) after all its reads -> row-local, race-free.
// ---------------------------------------------------------------------------
__global__ __launch_bounds__(256) void final_kernel(const float* __restrict__ SV,
                                                    const float* __restrict__ WscaleP,
                                                    float* __restrict__ out) {
  __shared__ float X[4096];
  int s = blockIdx.x, t = threadIdx.x, l = t & 63, w = t >> 6;
  const u16* zr = (const u16*)out + (size_t)s * 8192;
  float v[16];
#pragma unroll
  for (int k = 0; k < 16; ++k) {
    int i = (w * 16 + k) * 64 + l;
    v[k] = bf2f(zr[i]) + bf2f(zr[4096 + i]);
  }
  fwht4096_regs(v, X, w, l);
  float gscale = WscaleP[0] * (1.0f / 263.68f);
  float* orow = out + (size_t)s * 4096;
#pragma unroll
  for (int k = 0; k < 16; ++k) {
    int i = (w * 16 + k) * 64 + l;
    orow[i] = v[k] * gscale * SV[i];
  }
}

// ---------------------------------------------------------------------------
extern "C" void kernel_launch(void* const* d_in, const int* in_sizes, int n_in,
                              void* d_out, int out_size, void* d_ws, size_t ws_size,
                              hipStream_t stream) {
  const float* x      = (const float*)d_in[0];   // [1,1024,4096]
  const float* SU     = (const float*)d_in[1];   // [4096]
  const float* SV     = (const float*)d_in[2];   // [4096]
  const float* Wscale = (const float*)d_in[3];   // scalar
  const float* loraA  = (const float*)d_in[4];   // [4096,64]
  const float* loraB  = (const float*)d_in[5];   // [64,4096]
  const int*   Qidxs  = (const int*)d_in[6];     // [4096,512]
  const int*   grid   = (const int*)d_in[7];     // [256]
  float* out = (float*)d_out;

  char* ws = (char*)d_ws;
  u16* Wd = (u16*)ws;                                   // [4096][4224] = 34,603,008 B
  u16* u  = (u16*)(ws + 34603008);                      // [1024][4224] =  8,650,752 B
  u16* At = (u16*)(ws + 34603008 + 8650752);            // [64][4096]   =    524,288 B
  u16* Bh = At;                                         // reused after transA
  float* P = (float*)(ws + 34603008 + 8650752 + 524288);// [4][1024][64] = 1,048,576 B
  u16* zP = (u16*)out;                                  // [1024][2][4096] bf16, in-place

  decode_kernel<<<8192, 256, 0, stream>>>(Qidxs, grid, Wd);
  prep_A_kernel<<<64, 256, 0, stream>>>(loraA, SV, Wscale, At);
  transA_kernel<<<64, 256, 0, stream>>>(At, Wd);
  prep_B_kernel<<<64, 256, 0, stream>>>(loraB, SU, Bh);   // At slot now free
  fwht_u_kernel<<<1024, 256, 0, stream>>>(x, SU, u);
  dim3 lg(8, 4);
  lr_gemm_kernel<<<lg, 256, 0, stream>>>(u, Bh, P);
  lr_reduce_kernel<<<256, 256, 0, stream>>>(P, u);
  dim3 gg(32, 8, 2);
  gemm_kernel<<<gg, 256, 0, stream>>>(u, Wd, zP);
  final_kernel<<<1024, 256, 0, stream>>>(SV, Wscale, out);
}

// Round 6
// 96.432 us; speedup vs baseline: 1.0215x; 1.0215x over previous
//
#include <hip/hip_runtime.h>
#include <hip/hip_bf16.h>

typedef unsigned short u16;
typedef float  floatx4 __attribute__((ext_vector_type(4)));
typedef short  bf16x8  __attribute__((ext_vector_type(8)));

#define GK 4224   // extended K = 4096 + 64 lora cols + 64 zero pad (2*33*64)

__device__ __forceinline__ u16 f2bf_rne(float f) {
  union { float f; unsigned int u; } v; v.f = f;
  unsigned int r = v.u + 0x7FFFu + ((v.u >> 16) & 1u);
  return (u16)(r >> 16);
}
__device__ __forceinline__ float bf2f(u16 h) {
  union { unsigned int u; float f; } v; v.u = ((unsigned int)h) << 16;
  return v.f;
}

// ===========================================================================
// In-register FWHT-4096 per block (4 waves): H4096 = H64(rows) (x) H64(cols).
// ===========================================================================
__device__ __forceinline__ void fwht4096_regs(float v[16], float* X, int w, int l) {
#pragma unroll
  for (int h = 1; h < 64; h <<= 1) {
#pragma unroll
    for (int k = 0; k < 16; ++k) {
      float o = __shfl_xor(v[k], h, 64);
      v[k] = (l & h) ? (o - v[k]) : (v[k] + o);
    }
  }
#pragma unroll
  for (int k = 0; k < 16; ++k) X[(w * 16 + k) * 64 + l] = v[k];
  __syncthreads();
  float s4 = (w & 1) ? -1.f : 1.f;
  float s5 = (w & 2) ? -1.f : 1.f;
#pragma unroll
  for (int k = 0; k < 16; ++k) {
    float x00 = X[(k     ) * 64 + l];
    float x01 = X[(k + 16) * 64 + l];
    float x10 = X[(k + 32) * 64 + l];
    float x11 = X[(k + 48) * 64 + l];
    v[k] = (x00 + s4 * x01) + s5 * (x10 + s4 * x11);
  }
#pragma unroll
  for (int h = 1; h < 16; h <<= 1) {
#pragma unroll
    for (int k = 0; k < 16; ++k) {
      if (!(k & h)) { float a = v[k], b = v[k ^ h]; v[k] = a + b; v[k ^ h] = a - b; }
    }
  }
}

// ---------------------------------------------------------------------------
// Kernel 1: decode E8P -> integer weights (exact in bf16), pitched rows of GK.
// ---------------------------------------------------------------------------
__global__ void decode_kernel(const int* __restrict__ codes,
                              const int* __restrict__ grid,
                              u16* __restrict__ Wd) {
  __shared__ int sgrid[256];
  int t = threadIdx.x;
  sgrid[t] = grid[t & 255];
  __syncthreads();
  int idx = blockIdx.x * 256 + t;            // 0 .. 4096*512-1
  int c = codes[idx];
  int abs_idx   = c & 255;
  int sign_bits = (c >> 8) & 127;
  int dlt       = 2 * ((c >> 15) & 1) - 1;   // 4*delta = ±1
  int packed    = sgrid[abs_idx];
  int par       = __popc(sign_bits) & 1;
  u16 w[8];
#pragma unroll
  for (int j = 0; j < 8; ++j) {
    int nib = (packed >> (4 * j)) & 15;
    int neg = (j < 7) ? ((sign_bits >> j) & 1) : par;
    int val = (neg ? -2 * nib : 2 * nib) + dlt;
    w[j] = f2bf_rne((float)val);             // exact: |val| <= 29
  }
  uint4 pk;
  pk.x = (unsigned)w[0] | ((unsigned)w[1] << 16);
  pk.y = (unsigned)w[2] | ((unsigned)w[3] << 16);
  pk.z = (unsigned)w[4] | ((unsigned)w[5] << 16);
  pk.w = (unsigned)w[6] | ((unsigned)w[7] << 16);
  int m = idx >> 9, g = idx & 511;
  ((uint4*)Wd)[(size_t)m * (GK / 8) + g] = pk;   // GK/8 = 528 uint4 per row
}

// ---------------------------------------------------------------------------
// Kernel 2: At[r][m] = bf16( (0.8*263.68/(4096*Wscale)) * H_M(SV o loraA[:,r]) )
// ---------------------------------------------------------------------------
__global__ __launch_bounds__(256) void prep_A_kernel(const float* __restrict__ loraA,
                                                     const float* __restrict__ SV,
                                                     const float* __restrict__ WscaleP,
                                                     u16* __restrict__ At) {
  __shared__ float X[4096];
  int r = blockIdx.x, t = threadIdx.x, l = t & 63, w = t >> 6;
  float v[16];
#pragma unroll
  for (int k = 0; k < 16; ++k) {
    int i = (w * 16 + k) * 64 + l;
    v[k] = loraA[(size_t)i * 64 + r] * SV[i];
  }
  fwht4096_regs(v, X, w, l);
  float factor = (0.8f * 263.68f / 4096.0f) / WscaleP[0];
#pragma unroll
  for (int k = 0; k < 16; ++k) {
    int i = (w * 16 + k) * 64 + l;
    At[(size_t)r * 4096 + i] = f2bf_rne(v[k] * factor);
  }
}

// ---------------------------------------------------------------------------
// Kernel 3: transpose At[64][4096] into Wd tail cols 4096..4159; zero 4160..4223
// ---------------------------------------------------------------------------
__global__ void transA_kernel(const u16* __restrict__ At, u16* __restrict__ Wd) {
  __shared__ u16 T[64][65];
  int m0 = blockIdx.x * 64, t = threadIdx.x;
  int c = t & 63, q = t >> 6;
#pragma unroll
  for (int j = 0; j < 16; ++j) {
    int r = q * 16 + j;
    T[r][c] = At[(size_t)r * 4096 + m0 + c];
  }
  __syncthreads();
#pragma unroll
  for (int j = 0; j < 16; ++j) {
    int m = q * 16 + j;
    Wd[(size_t)(m0 + m) * GK + 4096 + c] = T[c][m];
    Wd[(size_t)(m0 + m) * GK + 4160 + c] = 0;   // K pad
  }
}

// ---------------------------------------------------------------------------
// Kernel 4: Bh[r][n] = bf16( Hnorm(loraB[r] o SU)[n] )  (orthonormal FWHT)
// lr[s,r] = x[s].loraB[r] = (x oSU).(loraB[r] oSU) = u[s].Bh[r]  (Parseval)
// ---------------------------------------------------------------------------
__global__ __launch_bounds__(256) void prep_B_kernel(const float* __restrict__ loraB,
                                                     const float* __restrict__ SU,
                                                     u16* __restrict__ Bh) {
  __shared__ float X[4096];
  int r = blockIdx.x, t = threadIdx.x, l = t & 63, w = t >> 6;
  float v[16];
#pragma unroll
  for (int k = 0; k < 16; ++k) {
    int i = (w * 16 + k) * 64 + l;
    v[k] = loraB[(size_t)r * 4096 + i] * SU[i];
  }
  fwht4096_regs(v, X, w, l);
#pragma unroll
  for (int k = 0; k < 16; ++k) {
    int i = (w * 16 + k) * 64 + l;
    Bh[(size_t)r * 4096 + i] = f2bf_rne(v[k] * 0.015625f);
  }
}

// ---------------------------------------------------------------------------
// Kernel 5: u[s][0..4095] = bf16( H(x[s] o SU) / 64 )
// ---------------------------------------------------------------------------
__global__ __launch_bounds__(256) void fwht_u_kernel(const float* __restrict__ x,
                                                     const float* __restrict__ SU,
                                                     u16* __restrict__ u) {
  __shared__ float X[4096];
  int s = blockIdx.x, t = threadIdx.x, l = t & 63, w = t >> 6;
  const float* xr = x + (size_t)s * 4096;
  float v[16];
#pragma unroll
  for (int k = 0; k < 16; ++k) {
    int i = (w * 16 + k) * 64 + l;
    v[k] = xr[i] * SU[i];
  }
  fwht4096_regs(v, X, w, l);
  u16* ur = u + (size_t)s * GK;
#pragma unroll
  for (int k = 0; k < 16; ++k) {
    int i = (w * 16 + k) * 64 + l;
    ur[i] = f2bf_rne(v[k] * 0.015625f);
  }
}

// ---------------------------------------------------------------------------
// Staging helpers (16B global_load_lds, XOR-swizzled source; verified r2-r5)
// ---------------------------------------------------------------------------
__device__ __forceinline__ void stage64(const u16* __restrict__ src, int rowBase,
                                        int kt, char* ldsBase, int wg, int l) {
#pragma unroll
  for (int it = 0; it < 4; ++it) {
    int ci  = it * 4 + wg;                // 1KB chunk index (wave-uniform)
    int row = ci * 8 + (l >> 3);
    int cg  = (l & 7) ^ ((l >> 3) & 7);   // pre-swizzled source 16B-slot
    const u16* gp = src + (size_t)(rowBase + row) * GK + kt + cg * 8;
    __builtin_amdgcn_global_load_lds(
        (const __attribute__((address_space(1))) void*)gp,
        (__attribute__((address_space(3))) void*)(ldsBase + ci * 1024), 16, 0, 0);
  }
}

// 64 rows x 64 cols, pitch 4096 (Bh)
__device__ __forceinline__ void stage64n(const u16* __restrict__ src,
                                         int kt, char* ldsBase, int wg, int l) {
#pragma unroll
  for (int it = 0; it < 2; ++it) {
    int ci  = it * 4 + wg;
    int row = ci * 8 + (l >> 3);
    int cg  = (l & 7) ^ ((l >> 3) & 7);
    const u16* gp = src + (size_t)row * 4096 + kt + cg * 8;
    __builtin_amdgcn_global_load_lds(
        (const __attribute__((address_space(1))) void*)gp,
        (__attribute__((address_space(3))) void*)(ldsBase + ci * 1024), 16, 0, 0);
  }
}

// ---------------------------------------------------------------------------
// Kernel 6: lr partials. P[by][s][r] = sum_{k in chunk by} u[s,k]*Bh[r,k]
// ---------------------------------------------------------------------------
__global__ __launch_bounds__(256) void lr_gemm_kernel(
    const u16* __restrict__ U,    // [1024][GK]
    const u16* __restrict__ Bh,   // [64][4096]
    float* __restrict__ P) {      // [4][1024][64]
  __shared__ char lds[49152];     // A0|A1 (16KB each) + B0|B1 (8KB each)
  int t = threadIdx.x, w = t >> 6, l = t & 63;
  int s0 = blockIdx.x * 128, k0 = blockIdx.y * 1024;
  int lr16 = l & 15, lk = l >> 4;
  char* ldsA = lds;
  char* ldsB = lds + 32768;

  floatx4 acc[2][4];
#pragma unroll
  for (int i = 0; i < 2; ++i)
#pragma unroll
    for (int j = 0; j < 4; ++j) acc[i][j] = (floatx4){0.f, 0.f, 0.f, 0.f};

  const int NT = 16;   // 16 * 64 = 1024
  stage64 (U,  s0, k0,      ldsA,         w, l);
  stage64n(Bh,     k0,      ldsB,         w, l);
  stage64 (U,  s0, k0 + 64, ldsA + 16384, w, l);
  stage64n(Bh,     k0 + 64, ldsB + 8192,  w, l);
  asm volatile("s_waitcnt vmcnt(6)" ::: "memory");
  __builtin_amdgcn_s_barrier();

  for (int i = 0; i < NT; ++i) {
    int buf = i & 1;
    const char* sAc = ldsA + buf * 16384;
    const char* sBc = ldsB + buf * 8192;
    bf16x8 a[2][2], b[4][2];
#pragma unroll
    for (int ii = 0; ii < 2; ++ii)
#pragma unroll
      for (int ks = 0; ks < 2; ++ks) {
        int row = w * 32 + ii * 16 + lr16;
        int kb  = ks * 64 + lk * 16;
        a[ii][ks] = *(const bf16x8*)(sAc + (row << 7) + (kb ^ ((row & 7) << 4)));
      }
#pragma unroll
    for (int jj = 0; jj < 4; ++jj)
#pragma unroll
      for (int ks = 0; ks < 2; ++ks) {
        int row = jj * 16 + lr16;
        int kb  = ks * 64 + lk * 16;
        b[jj][ks] = *(const bf16x8*)(sBc + (row << 7) + (kb ^ ((row & 7) << 4)));
      }
    asm volatile("s_waitcnt lgkmcnt(0)" ::: "memory");
    __builtin_amdgcn_sched_barrier(0);
    bool do_stage = (i + 2) < NT;
    if (do_stage) {
      __builtin_amdgcn_s_barrier();
      stage64 (U,  s0, k0 + (i + 2) * 64, ldsA + buf * 16384, w, l);
      stage64n(Bh,     k0 + (i + 2) * 64, ldsB + buf * 8192,  w, l);
    }
#pragma unroll
    for (int ks = 0; ks < 2; ++ks)
#pragma unroll
      for (int ii = 0; ii < 2; ++ii)
#pragma unroll
        for (int jj = 0; jj < 4; ++jj)
          acc[ii][jj] = __builtin_amdgcn_mfma_f32_16x16x32_bf16(
              a[ii][ks], b[jj][ks], acc[ii][jj], 0, 0, 0);
    if (i + 1 < NT) {
      if (do_stage) asm volatile("s_waitcnt vmcnt(6)" ::: "memory");
      else          asm volatile("s_waitcnt vmcnt(0)" ::: "memory");
      __builtin_amdgcn_s_barrier();
    }
  }
  float* Pb = P + (size_t)blockIdx.y * 65536;
#pragma unroll
  for (int ii = 0; ii < 2; ++ii)
#pragma unroll
    for (int jj = 0; jj < 4; ++jj) {
      int col  = jj * 16 + lr16;
      int rowb = s0 + w * 32 + ii * 16 + lk * 4;
#pragma unroll
      for (int q = 0; q < 4; ++q)
        Pb[(size_t)(rowb + q) * 64 + col] = acc[ii][jj][q];
    }
}

// ---------------------------------------------------------------------------
// Kernel 7: lr tail: u[s][4096+r] = bf16( sum_c P[c][s][r] ); zero K pad.
// ---------------------------------------------------------------------------
__global__ void lr_reduce_kernel(const float* __restrict__ P, u16* __restrict__ u) {
  int idx = blockIdx.x * 256 + threadIdx.x;   // 0..65535
  float s = P[idx] + P[65536 + idx] + P[131072 + idx] + P[196608 + idx];
  int ss = idx >> 6, rr = idx & 63;
  u[(size_t)ss * GK + 4096 + rr] = f2bf_rne(s);
  u[(size_t)ss * GK + 4160 + rr] = 0;         // K pad
}

// ---------------------------------------------------------------------------
// Kernel 8: GEMM partials with fragment prefetch + issue-early staging.
// zP[s][g][m] = bf16( sum_{k in half g} A[s,k]*B[m,k] ). Grid (32,8,2),
// 256 thr, 64 KiB LDS -> 2 independent blocks/CU. Per iteration:
//   stage(i+2) | MFMA ks0 (frags i, in regs) | vmcnt(8)+bar (tile i+1 ready,
//   staged a full iter ago) | read frags(i+1) | MFMA ks1 (overlaps reads) |
//   lgkm(0)+bar. Both waits land where they're ~free. T5 setprio on MFMA.
// ---------------------------------------------------------------------------
__device__ __forceinline__ void read_frags(const char* lds, int buf,
                                           int wm, int wn, int lr16, int lk,
                                           bf16x8 a[4][2], bf16x8 b[4][2]) {
  const char* sAc = lds + buf * 16384;
  const char* sBc = lds + 32768 + buf * 16384;
#pragma unroll
  for (int ii = 0; ii < 4; ++ii)
#pragma unroll
    for (int ks = 0; ks < 2; ++ks) {
      int row = wm * 64 + ii * 16 + lr16;
      a[ii][ks] = *(const bf16x8*)(sAc + (row << 7) + ((ks * 64 + lk * 16) ^ ((row & 7) << 4)));
    }
#pragma unroll
  for (int jj = 0; jj < 4; ++jj)
#pragma unroll
    for (int ks = 0; ks < 2; ++ks) {
      int row = wn * 64 + jj * 16 + lr16;
      b[jj][ks] = *(const bf16x8*)(sBc + (row << 7) + ((ks * 64 + lk * 16) ^ ((row & 7) << 4)));
    }
}

template<int KS>
__device__ __forceinline__ void mfma_cluster(const bf16x8 a[4][2], const bf16x8 b[4][2],
                                             floatx4 acc[4][4]) {
  __builtin_amdgcn_s_setprio(1);
#pragma unroll
  for (int ii = 0; ii < 4; ++ii)
#pragma unroll
    for (int jj = 0; jj < 4; ++jj)
      acc[ii][jj] = __builtin_amdgcn_mfma_f32_16x16x32_bf16(a[ii][KS], b[jj][KS], acc[ii][jj], 0, 0, 0);
  __builtin_amdgcn_s_setprio(0);
}

__device__ __forceinline__ void gemm_iter(int i, const u16* __restrict__ A,
                                          const u16* __restrict__ B,
                                          int s0, int m0, int kb0, char* lds,
                                          int w, int l, int wm, int wn, int lr16, int lk,
                                          const bf16x8 aC[4][2], const bf16x8 bC[4][2],
                                          bf16x8 aN[4][2], bf16x8 bN[4][2],
                                          floatx4 acc[4][4]) {
  const int NT = 33;
  int buf = i & 1;
  bool do_stage = (i + 2) < NT;              // block-uniform
  if (do_stage) {                            // issue-early: completion has a full iter
    stage64(A, s0, kb0 + (i + 2) * 64, lds + buf * 16384, w, l);
    stage64(B, m0, kb0 + (i + 2) * 64, lds + 32768 + buf * 16384, w, l);
  }
  mfma_cluster<0>(aC, bC, acc);              // frags(i) already in regs
  if (do_stage) asm volatile("s_waitcnt vmcnt(8)" ::: "memory");  // S(i+1) done
  else          asm volatile("s_waitcnt vmcnt(0)" ::: "memory");  // tail drain
  __builtin_amdgcn_s_barrier();              // all waves see tile(i+1)
  read_frags(lds, (i + 1) & 1, wm, wn, lr16, lk, aN, bN);
  mfma_cluster<1>(aC, bC, acc);              // overlaps the 16 ds_reads
  asm volatile("s_waitcnt lgkmcnt(0)" ::: "memory");
  __builtin_amdgcn_sched_barrier(0);
  __builtin_amdgcn_s_barrier();              // frags(i+1) read on all waves ->
}                                            // next iter may overwrite buf (i+1)&1... (stages go to buf i&1^1 pattern, safe)

__global__ __launch_bounds__(256) void gemm_kernel(
    const u16* __restrict__ A,   // u  [1024][GK]
    const u16* __restrict__ B,   // Wd [4096][GK]
    u16* __restrict__ zP) {      // [1024][2][4096] bf16 (aliases d_out)
  __shared__ char lds[65536];    // A0 A1 B0 B1 (16KB each)
  int t = threadIdx.x, w = t >> 6, l = t & 63;
  int m0 = blockIdx.x * 128, s0 = blockIdx.y * 128, g = blockIdx.z;
  int wm = w >> 1, wn = w & 1;
  int lr16 = l & 15, lk = l >> 4;

  floatx4 acc[4][4];
#pragma unroll
  for (int i = 0; i < 4; ++i)
#pragma unroll
    for (int j = 0; j < 4; ++j) acc[i][j] = (floatx4){0.f, 0.f, 0.f, 0.f};

  int kb0 = g * 2112;                        // 33*64 per half

  stage64(A, s0, kb0,      lds,         w, l);
  stage64(B, m0, kb0,      lds + 32768, w, l);
  stage64(A, s0, kb0 + 64, lds + 16384, w, l);
  stage64(B, m0, kb0 + 64, lds + 49152, w, l);
  asm volatile("s_waitcnt vmcnt(8)" ::: "memory");   // tile 0 landed
  __builtin_amdgcn_s_barrier();

  bf16x8 a0[4][2], b0[4][2], a1[4][2], b1[4][2];
  read_frags(lds, 0, wm, wn, lr16, lk, a0, b0);      // frags(0) -> set0
  asm volatile("s_waitcnt lgkmcnt(0)" ::: "memory");
  __builtin_amdgcn_sched_barrier(0);
  __builtin_amdgcn_s_barrier();                      // all waves hold frags(0)

  for (int i = 0; i < 32; i += 2) {                  // pair-unrolled: static reg sets
    gemm_iter(i,     A, B, s0, m0, kb0, lds, w, l, wm, wn, lr16, lk, a0, b0, a1, b1, acc);
    gemm_iter(i + 1, A, B, s0, m0, kb0, lds, w, l, wm, wn, lr16, lk, a1, b1, a0, b0, acc);
  }
  // peeled final iteration i=32 (even -> set0), no stage, no prefetch
  mfma_cluster<0>(a0, b0, acc);
  mfma_cluster<1>(a0, b0, acc);

  // C/D layout: col = lane&15, row = (lane>>4)*4 + q
#pragma unroll
  for (int ii = 0; ii < 4; ++ii)
#pragma unroll
    for (int jj = 0; jj < 4; ++jj) {
      int col  = m0 + wn * 64 + jj * 16 + lr16;
      int rowb = s0 + wm * 64 + ii * 16 + lk * 4;
#pragma unroll
      for (int q = 0; q < 4; ++q)
        zP[(size_t)(rowb + q) * 8192 + g * 4096 + col] = f2bf_rne(acc[ii][jj][q]);
    }
}

// ---------------------------------------------------------------------------
// Kernel 9: out[s][i] = (Wscale/263.68) * SV[i] * H(zP[s][0]+zP[s][1])[i]
// zP aliases out rows: block s reads bytes [s*16K, s*16K+16K) (as u16) and
// writes the same range (as f32) after all its reads -> row-local, race-free.
// ---------------------------------------------------------------------------
__global__ __launch_bounds__(256) void final_kernel(const float* __restrict__ SV,
                                                    const float* __restrict__ WscaleP,
                                                    float* __restrict__ out) {
  __shared__ float X[4096];
  int s = blockIdx.x, t = threadIdx.x, l = t & 63, w = t >> 6;
  const u16* zr = (const u16*)out + (size_t)s * 8192;
  float v[16];
#pragma unroll
  for (int k = 0; k < 16; ++k) {
    int i = (w * 16 + k) * 64 + l;
    v[k] = bf2f(zr[i]) + bf2f(zr[4096 + i]);
  }
  fwht4096_regs(v, X, w, l);
  float gscale = WscaleP[0] * (1.0f / 263.68f);
  float* orow = out + (size_t)s * 4096;
#pragma unroll
  for (int k = 0; k < 16; ++k) {
    int i = (w * 16 + k) * 64 + l;
    orow[i] = v[k] * gscale * SV[i];
  }
}

// ---------------------------------------------------------------------------
extern "C" void kernel_launch(void* const* d_in, const int* in_sizes, int n_in,
                              void* d_out, int out_size, void* d_ws, size_t ws_size,
                              hipStream_t stream) {
  const float* x      = (const float*)d_in[0];   // [1,1024,4096]
  const float* SU     = (const float*)d_in[1];   // [4096]
  const float* SV     = (const float*)d_in[2];   // [4096]
  const float* Wscale = (const float*)d_in[3];   // scalar
  const float* loraA  = (const float*)d_in[4];   // [4096,64]
  const float* loraB  = (const float*)d_in[5];   // [64,4096]
  const int*   Qidxs  = (const int*)d_in[6];     // [4096,512]
  const int*   grid   = (const int*)d_in[7];     // [256]
  float* out = (float*)d_out;

  char* ws = (char*)d_ws;
  u16* Wd = (u16*)ws;                                   // [4096][4224] = 34,603,008 B
  u16* u  = (u16*)(ws + 34603008);                      // [1024][4224] =  8,650,752 B
  u16* At = (u16*)(ws + 34603008 + 8650752);            // [64][4096]   =    524,288 B
  u16* Bh = At;                                         // reused after transA
  float* P = (float*)(ws + 34603008 + 8650752 + 524288);// [4][1024][64] = 1,048,576 B
  u16* zP = (u16*)out;                                  // [1024][2][4096] bf16, in-place

  decode_kernel<<<8192, 256, 0, stream>>>(Qidxs, grid, Wd);
  prep_A_kernel<<<64, 256, 0, stream>>>(loraA, SV, Wscale, At);
  transA_kernel<<<64, 256, 0, stream>>>(At, Wd);
  prep_B_kernel<<<64, 256, 0, stream>>>(loraB, SU, Bh);   // At slot now free
  fwht_u_kernel<<<1024, 256, 0, stream>>>(x, SU, u);
  dim3 lg(8, 4);
  lr_gemm_kernel<<<lg, 256, 0, stream>>>(u, Bh, P);
  lr_reduce_kernel<<<256, 256, 0, stream>>>(P, u);
  dim3 gg(32, 8, 2);
  gemm_kernel<<<gg, 256, 0, stream>>>(u, Wd, zP);
  final_kernel<<<1024, 256, 0, stream>>>(SV, Wscale, out);
}